// Round 1
// baseline (933.206 us; speedup 1.0000x reference)
//
#include <hip/hip_runtime.h>

#define S  2048
#define DH 64
#define NB 32

typedef float f32x4  __attribute__((ext_vector_type(4)));
typedef short bf16x8 __attribute__((ext_vector_type(8)));

__device__ __forceinline__ short f2bf(float f) {
  union { float f; unsigned u; } v; v.f = f;
  unsigned r = v.u + 0x7FFFu + ((v.u >> 16) & 1u);  // RNE
  return (short)(r >> 16);
}

// load 8 consecutive floats, convert to bf16x8 (A/B fragment half)
__device__ __forceinline__ bf16x8 load8_bf16(const float* p) {
  const float4* p4 = (const float4*)p;
  float4 a = p4[0], b = p4[1];
  bf16x8 o;
  o[0] = f2bf(a.x); o[1] = f2bf(a.y); o[2] = f2bf(a.z); o[3] = f2bf(a.w);
  o[4] = f2bf(b.x); o[5] = f2bf(b.y); o[6] = f2bf(b.z); o[7] = f2bf(b.w);
  return o;
}

// Fragment layouts (verified, m89/m91): 16x16x32 bf16
//   A: lane holds A[m = lane&15][k = (lane>>4)*8 + j], j=0..7
//   B: lane holds B[k = (lane>>4)*8 + j][n = lane&15]
//   C/D: reg r holds D[row = (lane>>4)*4 + r][col = lane&15]
__launch_bounds__(256, 2)
__global__ void attn_kernel(const float* __restrict__ Q, const float* __restrict__ K,
                            const float* __restrict__ V, float* __restrict__ Out,
                            float* __restrict__ Attn) {
  // ptile: per-wave P round-trip (C-layout -> A-layout); rows 0..63 of Q tile,
  // cols = local 0..63 within the wave's 64-col slice. +8 pad keeps b128 reads 2-way (free).
  __shared__ short ptile[4][64][72];   // 36864 B
  __shared__ float obuf[64][68];       // 17408 B  cross-wave output reduction
  __shared__ float rs[64][4];          // 1024 B   per-wave row sums

  const int b     = blockIdx.x >> 5;
  const int qbase = (blockIdx.x & 31) * 64;
  const int tid   = threadIdx.x;
  const int w     = tid >> 6;
  const int lane  = tid & 63;
  const int quad  = lane >> 4;
  const int col   = lane & 15;

  const float* Qb = Q + (size_t)b * S * DH;
  const float* Kb = K + (size_t)b * S * DH;
  const float* Vb = V + (size_t)b * S * DH;
  float* Ab = Attn + (size_t)b * S * S;

  // Q A-fragments: 4 row-tiles x 2 k-steps, resident in VGPRs for the whole block
  bf16x8 qa[4][2];
#pragma unroll
  for (int rt = 0; rt < 4; ++rt) {
    int row = qbase + rt * 16 + col;
#pragma unroll
    for (int kc = 0; kc < 2; ++kc)
      qa[rt][kc] = load8_bf16(Qb + row * DH + kc * 32 + quad * 8);
  }

  // ================= phase 1: per-row sum of exp(score) =================
  float l[4][4];
#pragma unroll
  for (int i = 0; i < 4; ++i)
#pragma unroll
    for (int j = 0; j < 4; ++j) l[i][j] = 0.f;

  for (int c = 0; c < 8; ++c) {
    const int cb = c * 256 + w * 64;   // this wave's 64-col slice
#pragma unroll
    for (int ct = 0; ct < 4; ++ct) {
      const int kcol = cb + ct * 16 + col;
      bf16x8 kb0 = load8_bf16(Kb + kcol * DH + quad * 8);
      bf16x8 kb1 = load8_bf16(Kb + kcol * DH + 32 + quad * 8);
#pragma unroll
      for (int rt = 0; rt < 4; ++rt) {
        f32x4 acc = {0.f, 0.f, 0.f, 0.f};
        acc = __builtin_amdgcn_mfma_f32_16x16x32_bf16(qa[rt][0], kb0, acc, 0, 0, 0);
        acc = __builtin_amdgcn_mfma_f32_16x16x32_bf16(qa[rt][1], kb1, acc, 0, 0, 0);
#pragma unroll
        for (int r = 0; r < 4; ++r) l[rt][r] += __expf(acc[r] * 0.125f);
      }
    }
  }

  // butterfly-sum over the 16 lanes of each quad (cols within the wave slice)
#pragma unroll
  for (int m = 1; m <= 8; m <<= 1)
#pragma unroll
    for (int rt = 0; rt < 4; ++rt)
#pragma unroll
      for (int r = 0; r < 4; ++r) l[rt][r] += __shfl_xor(l[rt][r], m, 64);

  if (col == 0) {
#pragma unroll
    for (int rt = 0; rt < 4; ++rt)
#pragma unroll
      for (int r = 0; r < 4; ++r) rs[rt * 16 + quad * 4 + r][w] = l[rt][r];
  }
  __syncthreads();

  float invl[4][4];
#pragma unroll
  for (int rt = 0; rt < 4; ++rt)
#pragma unroll
    for (int r = 0; r < 4; ++r) {
      const float4 t = *(const float4*)&rs[rt * 16 + quad * 4 + r][0];
      invl[rt][r] = 1.0f / (t.x + t.y + t.z + t.w);
    }

  // ================= phase 2: write attn, accumulate PV =================
  f32x4 oacc[4][4];  // [row-tile][dim-tile]
#pragma unroll
  for (int i = 0; i < 4; ++i)
#pragma unroll
    for (int j = 0; j < 4; ++j) oacc[i][j] = (f32x4){0.f, 0.f, 0.f, 0.f};

  for (int c = 0; c < 8; ++c) {
    const int cb = c * 256 + w * 64;
#pragma unroll
    for (int ct = 0; ct < 4; ++ct) {
      const int kcol = cb + ct * 16 + col;
      bf16x8 kb0 = load8_bf16(Kb + kcol * DH + quad * 8);
      bf16x8 kb1 = load8_bf16(Kb + kcol * DH + 32 + quad * 8);
#pragma unroll
      for (int rt = 0; rt < 4; ++rt) {
        f32x4 acc = {0.f, 0.f, 0.f, 0.f};
        acc = __builtin_amdgcn_mfma_f32_16x16x32_bf16(qa[rt][0], kb0, acc, 0, 0, 0);
        acc = __builtin_amdgcn_mfma_f32_16x16x32_bf16(qa[rt][1], kb1, acc, 0, 0, 0);
#pragma unroll
        for (int r = 0; r < 4; ++r) {
          const float p = __expf(acc[r] * 0.125f) * invl[rt][r];
          const int row = rt * 16 + quad * 4 + r;
          Ab[(size_t)(qbase + row) * S + kcol] = p;       // 16-lane (64B) segments
          ptile[w][row][ct * 16 + col] = f2bf(p);         // C-layout scatter (wave-private)
        }
      }
    }
    // PV: oacc += P[64 x 64] * V[64 x 64]  (wave-synchronous LDS round-trip, no barrier)
#pragma unroll
    for (int ks = 0; ks < 2; ++ks) {
      bf16x8 pa[4];
#pragma unroll
      for (int mt = 0; mt < 4; ++mt)
        pa[mt] = *(const bf16x8*)&ptile[w][mt * 16 + col][ks * 32 + quad * 8];
#pragma unroll
      for (int nt = 0; nt < 4; ++nt) {
        bf16x8 vb;
#pragma unroll
        for (int j = 0; j < 8; ++j)
          vb[j] = f2bf(Vb[(cb + ks * 32 + quad * 8 + j) * DH + nt * 16 + col]);
#pragma unroll
        for (int mt = 0; mt < 4; ++mt)
          oacc[mt][nt] = __builtin_amdgcn_mfma_f32_16x16x32_bf16(pa[mt], vb, oacc[mt][nt], 0, 0, 0);
      }
    }
  }

  // ============ cross-wave reduction of output, then coalesced store ============
  for (int wv = 0; wv < 4; ++wv) {
    if (w == wv) {
#pragma unroll
      for (int mt = 0; mt < 4; ++mt)
#pragma unroll
        for (int nt = 0; nt < 4; ++nt)
#pragma unroll
          for (int r = 0; r < 4; ++r) {
            const int row = mt * 16 + quad * 4 + r;
            if (wv == 0) obuf[row][nt * 16 + col]  = oacc[mt][nt][r];
            else         obuf[row][nt * 16 + col] += oacc[mt][nt][r];
          }
    }
    __syncthreads();
  }

  {
    const int row = tid >> 2;
    const int seg = (tid & 3) * 16;
    float* gp = Out + ((size_t)b * S + qbase + row) * DH + seg;
#pragma unroll
    for (int j = 0; j < 4; ++j) {
      const float4 vv = *(const float4*)&obuf[row][seg + j * 4];
      ((float4*)gp)[j] = vv;
    }
  }
}

extern "C" void kernel_launch(void* const* d_in, const int* in_sizes, int n_in,
                              void* d_out, int out_size, void* d_ws, size_t ws_size,
                              hipStream_t stream) {
  const float* q = (const float*)d_in[0];
  const float* k = (const float*)d_in[1];
  const float* v = (const float*)d_in[2];
  float* outp = (float*)d_out;                                  // [32,2048,64]
  float* attn = (float*)d_out + (size_t)NB * S * DH;            // [32,2048,2048]
  attn_kernel<<<dim3(NB * (S / 64)), dim3(256), 0, stream>>>(q, k, v, outp, attn);
}